// Round 5
// baseline (229.910 us; speedup 1.0000x reference)
//
#include <hip/hip_runtime.h>
#include <hip/hip_bf16.h>
#include <math.h>

// Problem constants (from reference)
#define BATCH 4
#define SEQL 256          // L = C = 256
#define DMODEL 1024
#define DINNER 2048
#define DSTATE 16
#define DTRANK 64
#define OUTC 1024
#define NROWS (BATCH * SEQL)   // 1024

typedef __attribute__((ext_vector_type(8))) short bf16x8;  // 8 bf16 = 4 VGPRs
typedef __attribute__((ext_vector_type(4))) float f32x4;   // MFMA C/D

// ---------------------------------------------------------------------------
// bf16 MFMA GEMM (m97 structure): C = A @ B^T, split-K over blockIdx.z.
// ---------------------------------------------------------------------------
__global__ __launch_bounds__(256) void gemm_mfma(const __hip_bfloat16* __restrict__ A,
                                                 const __hip_bfloat16* __restrict__ B,
                                                 float* __restrict__ C,
                                                 int M, int N, int K,
                                                 int lda, int ldb) {
    __shared__ __hip_bfloat16 As[128 * 32];   // row-major [128][32]
    __shared__ __hip_bfloat16 Bs[128 * 32];
    const int t  = threadIdx.x;
    const int w  = t >> 6;          // wave 0..3
    const int ln = t & 63;
    const int wm = w >> 1, wn = w & 1;
    const int q  = ln >> 4, lr = ln & 15;
    const int m0 = blockIdx.y * 128;
    const int n0 = blockIdx.x * 128;
    const int Kpart = K / gridDim.z;
    const int kbase = blockIdx.z * Kpart;

    f32x4 acc[4][4] = {};

    const __hip_bfloat16* Ag = A + (size_t)m0 * lda + kbase;
    const __hip_bfloat16* Bg = B + (size_t)n0 * ldb + kbase;

    for (int k0 = 0; k0 < Kpart; k0 += 32) {
        #pragma unroll
        for (int i = 0; i < 2; ++i) {
            const int c = (i * 4 + w) * 64 + ln;
            const int r = c >> 2, col = (c & 3) * 8;
            __builtin_amdgcn_global_load_lds(
                (const __attribute__((address_space(1))) void*)(Ag + (size_t)r * lda + k0 + col),
                (__attribute__((address_space(3))) void*)(As + (i * 4 + w) * 64 * 8),
                16, 0, 0);
            __builtin_amdgcn_global_load_lds(
                (const __attribute__((address_space(1))) void*)(Bg + (size_t)r * ldb + k0 + col),
                (__attribute__((address_space(3))) void*)(Bs + (i * 4 + w) * 64 * 8),
                16, 0, 0);
        }
        __syncthreads();
        bf16x8 af[4], bfr[4];
        #pragma unroll
        for (int i = 0; i < 4; ++i)
            af[i] = *(const bf16x8*)(As + (wm * 64 + i * 16 + lr) * 32 + q * 8);
        #pragma unroll
        for (int j = 0; j < 4; ++j)
            bfr[j] = *(const bf16x8*)(Bs + (wn * 64 + j * 16 + lr) * 32 + q * 8);
        #pragma unroll
        for (int i = 0; i < 4; ++i)
            #pragma unroll
            for (int j = 0; j < 4; ++j)
                acc[i][j] = __builtin_amdgcn_mfma_f32_16x16x32_bf16(af[i], bfr[j], acc[i][j], 0, 0, 0);
        __syncthreads();
    }
    float* Cz = C + (size_t)blockIdx.z * M * N;
    #pragma unroll
    for (int i = 0; i < 4; ++i) {
        const int mrow = m0 + wm * 64 + i * 16 + q * 4;
        #pragma unroll
        for (int j = 0; j < 4; ++j) {
            const int ncol = n0 + wn * 64 + j * 16 + lr;
            #pragma unroll
            for (int r = 0; r < 4; ++r)
                Cz[(size_t)(mrow + r) * N + ncol] = acc[i][j][r];
        }
    }
}

// ---------------------------------------------------------------------------
// dt_proj as MFMA GEMM with fused bias + softplus epilogue.
// ---------------------------------------------------------------------------
__global__ __launch_bounds__(256) void gemm_dtsp(const __hip_bfloat16* __restrict__ A,
                                                 const __hip_bfloat16* __restrict__ B,
                                                 const float* __restrict__ bd,
                                                 float* __restrict__ delta) {
    __shared__ __hip_bfloat16 As[128 * 32];
    __shared__ __hip_bfloat16 Bs[128 * 32];
    const int t  = threadIdx.x;
    const int w  = t >> 6;
    const int ln = t & 63;
    const int wm = w >> 1, wn = w & 1;
    const int q  = ln >> 4, lr = ln & 15;
    const int m0 = blockIdx.y * 128;
    const int n0 = blockIdx.x * 128;
    const int lda = 128, ldb = 64, N = 2048;

    f32x4 acc[4][4] = {};
    const __hip_bfloat16* Ag = A + (size_t)m0 * lda;
    const __hip_bfloat16* Bg = B + (size_t)n0 * ldb;

    for (int k0 = 0; k0 < 64; k0 += 32) {
        #pragma unroll
        for (int i = 0; i < 2; ++i) {
            const int c = (i * 4 + w) * 64 + ln;
            const int r = c >> 2, col = (c & 3) * 8;
            __builtin_amdgcn_global_load_lds(
                (const __attribute__((address_space(1))) void*)(Ag + (size_t)r * lda + k0 + col),
                (__attribute__((address_space(3))) void*)(As + (i * 4 + w) * 64 * 8),
                16, 0, 0);
            __builtin_amdgcn_global_load_lds(
                (const __attribute__((address_space(1))) void*)(Bg + (size_t)r * ldb + k0 + col),
                (__attribute__((address_space(3))) void*)(Bs + (i * 4 + w) * 64 * 8),
                16, 0, 0);
        }
        __syncthreads();
        bf16x8 af[4], bfr[4];
        #pragma unroll
        for (int i = 0; i < 4; ++i)
            af[i] = *(const bf16x8*)(As + (wm * 64 + i * 16 + lr) * 32 + q * 8);
        #pragma unroll
        for (int j = 0; j < 4; ++j)
            bfr[j] = *(const bf16x8*)(Bs + (wn * 64 + j * 16 + lr) * 32 + q * 8);
        #pragma unroll
        for (int i = 0; i < 4; ++i)
            #pragma unroll
            for (int j = 0; j < 4; ++j)
                acc[i][j] = __builtin_amdgcn_mfma_f32_16x16x32_bf16(af[i], bfr[j], acc[i][j], 0, 0, 0);
        __syncthreads();
    }
    #pragma unroll
    for (int i = 0; i < 4; ++i) {
        const int mrow = m0 + wm * 64 + i * 16 + q * 4;
        #pragma unroll
        for (int j = 0; j < 4; ++j) {
            const int ncol = n0 + wn * 64 + j * 16 + lr;
            const float bias = bd[ncol];
            #pragma unroll
            for (int r = 0; r < 4; ++r) {
                float v = acc[i][j][r] + bias;
                float sp = (v > 20.f) ? v : log1pf(__expf(v));
                delta[(size_t)(mrow + r) * N + ncol] = sp;
            }
        }
    }
}

// ---------------------------------------------------------------------------
// Reduce 8 split-K partials of x_proj -> xdbl fp32 (1024x128) + xdblb bf16.
// ---------------------------------------------------------------------------
__global__ void xdbl_reduce_kernel(const float* __restrict__ part,
                                   float* __restrict__ xdbl,
                                   __hip_bfloat16* __restrict__ xdblb) {
    const int i = blockIdx.x * 256 + threadIdx.x;   // 1024*128
    float s = 0.f;
    #pragma unroll
    for (int z = 0; z < 8; ++z) s += part[(size_t)z * (1024 * 128) + i];
    xdbl[i] = s;
    xdblb[i] = __float2bfloat16(s);
}

// ---------------------------------------------------------------------------
// Fused fp32 -> bf16 casts for all weight/activation inputs.
// ---------------------------------------------------------------------------
#define R0 (1024 * 1024)
#define R1 (R0 + 4096 * 1024)
#define R2 (R1 + 2048 * 1024)
#define R3 (R2 + 128 * 2048)
#define R4 (R3 + 2048 * 64)
__global__ void cast_all_kernel(const float* __restrict__ x1,
                                const float* __restrict__ w_in,
                                const float* __restrict__ w_out,
                                const float* __restrict__ w_xp,
                                const float* __restrict__ w_dt,
                                __hip_bfloat16* __restrict__ xa,
                                __hip_bfloat16* __restrict__ wb1,
                                __hip_bfloat16* __restrict__ wob,
                                __hip_bfloat16* __restrict__ wpb,
                                __hip_bfloat16* __restrict__ wdb) {
    int i = blockIdx.x * 256 + threadIdx.x;
    if (i < R0) {
        xa[i] = __float2bfloat16(x1[i]);
    } else if (i < R1) {
        int j = i - R0; wb1[j] = __float2bfloat16(w_in[j]);
    } else if (i < R2) {
        int j = i - R1; wob[j] = __float2bfloat16(w_out[j]);
    } else if (i < R3) {
        int j = i - R2; int e = j >> 11;
        wpb[j] = __float2bfloat16(e < 96 ? w_xp[j] : 0.f);
    } else if (i < R4) {
        int j = i - R3; wdb[j] = __float2bfloat16(w_dt[j]);
    }
}

// ---------------------------------------------------------------------------
// Depthwise causal conv1d (k=4, left pad 3) + bias + SiLU.
// ---------------------------------------------------------------------------
__global__ void conv_silu_kernel(const float* __restrict__ xz,
                                 const float* __restrict__ conv_w,
                                 const float* __restrict__ conv_b,
                                 float* __restrict__ xs,
                                 __hip_bfloat16* __restrict__ xsb) {
    int idx = blockIdx.x * blockDim.x + threadIdx.x;  // (b*L + l)*DINNER + d
    int d = idx & (DINNER - 1);
    int l = (idx >> 11) & (SEQL - 1);
    int b = idx >> 19;
    const float w0 = conv_w[d * 4 + 0];
    const float w1 = conv_w[d * 4 + 1];
    const float w2 = conv_w[d * 4 + 2];
    const float w3 = conv_w[d * 4 + 3];
    float acc = conv_b[d];
    const size_t base = (size_t)(b * SEQL) * (2 * DINNER) + d;
    if (l >= 3) acc += w0 * xz[base + (size_t)(l - 3) * (2 * DINNER)];
    if (l >= 2) acc += w1 * xz[base + (size_t)(l - 2) * (2 * DINNER)];
    if (l >= 1) acc += w2 * xz[base + (size_t)(l - 1) * (2 * DINNER)];
    acc += w3 * xz[base + (size_t)l * (2 * DINNER)];
    float v = acc / (1.f + __expf(-acc));
    xs[idx] = v;
    xsb[idx] = __float2bfloat16(v);
}

// ---------------------------------------------------------------------------
// 16-lane row sum via DPP row_ror rotations (no DS ops).
// ---------------------------------------------------------------------------
__device__ __forceinline__ float row_reduce16(float x) {
    x += __int_as_float(__builtin_amdgcn_update_dpp(0, __float_as_int(x), 0x128, 0xF, 0xF, true));
    x += __int_as_float(__builtin_amdgcn_update_dpp(0, __float_as_int(x), 0x124, 0xF, 0xF, true));
    x += __int_as_float(__builtin_amdgcn_update_dpp(0, __float_as_int(x), 0x122, 0xF, 0xF, true));
    x += __int_as_float(__builtin_amdgcn_update_dpp(0, __float_as_int(x), 0x121, 0xF, 0xF, true));
    return x;
}

// ---------------------------------------------------------------------------
// Selective scan, LDS double-buffered (ping-pong), ONE barrier per chunk.
// Block = (16 d) x (16 n) = 256 threads; grid (DINNER/16, B) = 512 blocks
// (exactly 2 blocks/CU — grid-capped occupancy). LDS = 2 x 24 KB = 48 KB.
// write_lds(c+1) targets buffer (c+1)&1 while compute(c) reads buffer c&1;
// region (c+1)&1 was last READ in compute(c-1), which every wave finished
// before the barrier ending iteration c-1 -> single barrier is sufficient.
// ---------------------------------------------------------------------------
#define CHUNK 64
__global__ __launch_bounds__(256) void scan_kernel(const float* __restrict__ delta,
                                                   const float* __restrict__ xs,
                                                   const float* __restrict__ xdbl,
                                                   const float* __restrict__ xz,
                                                   const float* __restrict__ A_log,
                                                   const float* __restrict__ Dp,
                                                   __hip_bfloat16* __restrict__ ybb) {
    __shared__ float sDU[2][CHUNK][16][2];   // [buf][l][dl][{dv, dv*xv}]
    __shared__ float sBC[2][CHUNK][16][2];   // [buf][l][n][{B, C}]
    __shared__ float sGW[2][CHUNK][16][2];   // [buf][l][dl][{g, D*xv*g}]
    const int b = blockIdx.y;
    const int dg = blockIdx.x;
    const int t = threadIdx.x;
    const int dl = t >> 4;
    const int n  = t & 15;
    const int d  = dg * 16 + dl;
    const float a = -__expf(A_log[d * DSTATE + n]);
    const int srow = t >> 4, scol = t & 15;
    const int sd = dg * 16 + scol;
    const float Dstage = Dp[sd];
    const int rowbase = b * SEQL;
    float h = 0.f;

    float rD[4], rX[4], rR[4], rB[4], rC[4];

    auto issue_loads = [&](int l0) {
        #pragma unroll
        for (int i = 0; i < 4; ++i) {
            const int row = rowbase + l0 + i * 16 + srow;
            rD[i] = delta[(size_t)row * DINNER + sd];
            rX[i] = xs[(size_t)row * DINNER + sd];
            rR[i] = xz[(size_t)row * (2 * DINNER) + DINNER + sd];
            rB[i] = xdbl[row * 128 + 64 + scol];
            rC[i] = xdbl[row * 128 + 80 + scol];
        }
    };
    auto write_lds = [&](int buf) {
        #pragma unroll
        for (int i = 0; i < 4; ++i) {
            const int row = i * 16 + srow;
            const float dv = rD[i], xv = rX[i], r = rR[i];
            const float g = r / (1.f + __expf(-r));
            sDU[buf][row][scol][0] = dv;
            sDU[buf][row][scol][1] = dv * xv;
            sGW[buf][row][scol][0] = g;
            sGW[buf][row][scol][1] = Dstage * xv * g;
            sBC[buf][row][scol][0] = rB[i];
            sBC[buf][row][scol][1] = rC[i];
        }
    };

    issue_loads(0);
    write_lds(0);
    __syncthreads();
    for (int c = 0; c < SEQL / CHUNK; ++c) {
        if (c + 1 < SEQL / CHUNK) issue_loads((c + 1) * CHUNK);
        const int buf = c & 1;
        const int l0 = c * CHUNK;
        #pragma unroll 32
        for (int l = 0; l < CHUNK; ++l) {
            const float dv = sDU[buf][l][dl][0];
            const float u  = sDU[buf][l][dl][1];
            const float bm = sBC[buf][l][n][0];
            const float cm = sBC[buf][l][n][1];
            const float e = __expf(dv * a);
            h = e * h + u * bm;
            float p = row_reduce16(h * cm);
            if (n == 0) {
                const float g  = sGW[buf][l][dl][0];
                const float wg = sGW[buf][l][dl][1];
                const float y = p * g + wg;
                ybb[(size_t)(rowbase + l0 + l) * DINNER + d] = __float2bfloat16(y);
            }
        }
        if (c + 1 < SEQL / CHUNK) write_lds((c + 1) & 1);
        __syncthreads();
    }
}

// ---------------------------------------------------------------------------
// LayerNorm over last dim (1024), fused 4-way split-K reduce of out_proj
// partials. block per row, 256 threads x 4 elems.
// ---------------------------------------------------------------------------
__global__ __launch_bounds__(256) void ln_kernel(const float* __restrict__ opart,
                                                 const float* __restrict__ lw,
                                                 const float* __restrict__ lb,
                                                 float* __restrict__ out) {
    __shared__ float red[8];
    const int row = blockIdx.x;
    const int t = threadIdx.x;
    float v[4];
    float s = 0.f, s2 = 0.f;
    #pragma unroll
    for (int i = 0; i < 4; ++i) {
        const int c = t + 256 * i;
        float acc = 0.f;
        #pragma unroll
        for (int z = 0; z < 4; ++z)
            acc += opart[(size_t)z * (1024 * 1024) + (size_t)row * OUTC + c];
        v[i] = acc;
        s += acc;
        s2 += acc * acc;
    }
    #pragma unroll
    for (int o = 32; o; o >>= 1) {
        s += __shfl_down(s, o);
        s2 += __shfl_down(s2, o);
    }
    const int wid = t >> 6;
    if ((t & 63) == 0) { red[wid] = s; red[4 + wid] = s2; }
    __syncthreads();
    if (t == 0) {
        float ts = red[0] + red[1] + red[2] + red[3];
        float ts2 = red[4] + red[5] + red[6] + red[7];
        float mu = ts * (1.f / OUTC);
        float var = ts2 * (1.f / OUTC) - mu * mu;
        red[0] = mu;
        red[1] = rsqrtf(var + 1e-5f);
    }
    __syncthreads();
    const float mu = red[0], rs = red[1];
    #pragma unroll
    for (int i = 0; i < 4; ++i) {
        const int c = t + 256 * i;
        out[(size_t)row * OUTC + c] = (v[i] - mu) * rs * lw[c] + lb[c];
    }
}

// ---------------------------------------------------------------------------
extern "C" void kernel_launch(void* const* d_in, const int* in_sizes, int n_in,
                              void* d_out, int out_size, void* d_ws, size_t ws_size,
                              hipStream_t stream) {
    const float* x1        = (const float*)d_in[0];   // (1024,1024)
    const float* in_proj_w = (const float*)d_in[1];   // (4096,1024)
    const float* conv_w    = (const float*)d_in[2];   // (2048,1,4)
    const float* conv_b    = (const float*)d_in[3];   // (2048,)
    const float* x_proj_w  = (const float*)d_in[4];   // (96,2048)
    const float* dt_proj_w = (const float*)d_in[5];   // (2048,64)
    const float* dt_proj_b = (const float*)d_in[6];   // (2048,)
    const float* A_log     = (const float*)d_in[7];   // (2048,16)
    const float* Dp        = (const float*)d_in[8];   // (2048,)
    const float* out_proj_w= (const float*)d_in[9];   // (1024,2048)
    const float* ln_w      = (const float*)d_in[10];  // (1024,)
    const float* ln_b      = (const float*)d_in[11];  // (1024,)
    float* out = (float*)d_out;

    // workspace carve-up
    char* p = (char*)d_ws;
    __hip_bfloat16* xa    = (__hip_bfloat16*)p; p += (size_t)1024 * 1024 * 2;  // 2 MB
    __hip_bfloat16* wb1   = (__hip_bfloat16*)p; p += (size_t)4096 * 1024 * 2;  // 8 MB
    __hip_bfloat16* wpb   = (__hip_bfloat16*)p; p += (size_t)128 * 2048 * 2;   // 0.5 MB
    __hip_bfloat16* wob   = (__hip_bfloat16*)p; p += (size_t)1024 * 2048 * 2;  // 4 MB
    __hip_bfloat16* wdb   = (__hip_bfloat16*)p; p += (size_t)2048 * 64 * 2;    // 0.25 MB
    __hip_bfloat16* xsb   = (__hip_bfloat16*)p; p += (size_t)1024 * 2048 * 2;  // 4 MB
    __hip_bfloat16* ybb   = (__hip_bfloat16*)p; p += (size_t)1024 * 2048 * 2;  // 4 MB
    __hip_bfloat16* xdblb = (__hip_bfloat16*)p; p += (size_t)1024 * 128 * 2;   // 0.25 MB
    float* xz    = (float*)p; p += (size_t)1024 * 4096 * 4;                    // 16 MB
    float* xs    = (float*)p; p += (size_t)1024 * 2048 * 4;                    // 8 MB
    float* xdbl  = (float*)p; p += (size_t)1024 * 128 * 4;                     // 0.5 MB
    float* xpart = (float*)p; p += (size_t)8 * 1024 * 128 * 4;                 // 4 MB
    float* delta = (float*)p; p += (size_t)1024 * 2048 * 4;                    // 8 MB
    // out_proj partials (16 MB) alias xz: scan (last reader of xz) precedes
    // out_proj in stream order.
    float* opart = xz;

    // 0. fused bf16 casts
    cast_all_kernel<<<(R4 + 255) / 256, 256, 0, stream>>>(x1, in_proj_w, out_proj_w,
                                                          x_proj_w, dt_proj_w,
                                                          xa, wb1, wob, wpb, wdb);
    // 1. in_proj: xz = xa @ wb1^T   (1024 x 4096, K=1024)
    gemm_mfma<<<dim3(32, 8, 1), 256, 0, stream>>>(xa, wb1, xz,
                                                  NROWS, 2 * DINNER, DMODEL, DMODEL, DMODEL);
    // 2. depthwise causal conv + SiLU -> xs (fp32) + xsb (bf16)
    conv_silu_kernel<<<(NROWS * DINNER) / 256, 256, 0, stream>>>(xz, conv_w, conv_b, xs, xsb);
    // 3. x_proj: xpart[z] = xsb @ wpb^T partials (1024 x 128, K=2048, split 8)
    gemm_mfma<<<dim3(1, 8, 8), 256, 0, stream>>>(xsb, wpb, xpart,
                                                 NROWS, 128, DINNER, DINNER, DINNER);
    xdbl_reduce_kernel<<<(1024 * 128) / 256, 256, 0, stream>>>(xpart, xdbl, xdblb);
    // 4. dt_proj + softplus -> delta (MFMA, K=64)
    gemm_dtsp<<<dim3(16, 8), 256, 0, stream>>>(xdblb, wdb, dt_proj_b, delta);
    // 5. selective scan + gate -> ybb (bf16)
    scan_kernel<<<dim3(DINNER / 16, BATCH), 256, 0, stream>>>(delta, xs, xdbl, xz,
                                                              A_log, Dp, ybb);
    // 6. out_proj partials: opart[z] = ybb @ wob^T (1024 x 1024, K=2048, split 4)
    gemm_mfma<<<dim3(8, 8, 4), 256, 0, stream>>>(ybb, wob, opart,
                                                 NROWS, OUTC, DINNER, DINNER, DINNER);
    // 7. LayerNorm (+ split-K reduce) -> out
    ln_kernel<<<NROWS, 256, 0, stream>>>(opart, ln_w, ln_b, out);
}

// Round 6
// 221.081 us; speedup vs baseline: 1.0399x; 1.0399x over previous
//
#include <hip/hip_runtime.h>
#include <hip/hip_bf16.h>
#include <math.h>

// Problem constants (from reference)
#define BATCH 4
#define SEQL 256          // L = C = 256
#define DMODEL 1024
#define DINNER 2048
#define DSTATE 16
#define DTRANK 64
#define OUTC 1024
#define NROWS (BATCH * SEQL)   // 1024
#define NCHUNK 4
#define CH 64             // SEQL / NCHUNK

typedef __attribute__((ext_vector_type(8))) short bf16x8;  // 8 bf16 = 4 VGPRs
typedef __attribute__((ext_vector_type(4))) float f32x4;   // MFMA C/D

// ---------------------------------------------------------------------------
// bf16 MFMA GEMM, LDS double-buffered with post-barrier prefetch.
// C = A @ B^T, split-K over blockIdx.z. At 1 block/CU (in_proj) there is no
// TLP, so the prefetch of tile k+1 issued AFTER the barrier overlaps the MFMA
// phase of tile k within each wave; the end-of-iter barrier drains it.
// ---------------------------------------------------------------------------
__global__ __launch_bounds__(256) void gemm_mfma(const __hip_bfloat16* __restrict__ A,
                                                 const __hip_bfloat16* __restrict__ B,
                                                 float* __restrict__ C,
                                                 int M, int N, int K,
                                                 int lda, int ldb) {
    __shared__ __hip_bfloat16 As[2][128 * 32];
    __shared__ __hip_bfloat16 Bs[2][128 * 32];
    const int t  = threadIdx.x;
    const int w  = t >> 6;          // wave 0..3
    const int ln = t & 63;
    const int wm = w >> 1, wn = w & 1;
    const int q  = ln >> 4, lr = ln & 15;
    const int m0 = blockIdx.y * 128;
    const int n0 = blockIdx.x * 128;
    const int Kpart = K / gridDim.z;
    const int kbase = blockIdx.z * Kpart;

    f32x4 acc[4][4] = {};

    const __hip_bfloat16* Ag = A + (size_t)m0 * lda + kbase;
    const __hip_bfloat16* Bg = B + (size_t)n0 * ldb + kbase;

    auto stage = [&](int k0, int buf) {
        #pragma unroll
        for (int i = 0; i < 2; ++i) {
            const int c = (i * 4 + w) * 64 + ln;
            const int r = c >> 2, col = (c & 3) * 8;
            __builtin_amdgcn_global_load_lds(
                (const __attribute__((address_space(1))) void*)(Ag + (size_t)r * lda + k0 + col),
                (__attribute__((address_space(3))) void*)(As[buf] + (i * 4 + w) * 64 * 8),
                16, 0, 0);
            __builtin_amdgcn_global_load_lds(
                (const __attribute__((address_space(1))) void*)(Bg + (size_t)r * ldb + k0 + col),
                (__attribute__((address_space(3))) void*)(Bs[buf] + (i * 4 + w) * 64 * 8),
                16, 0, 0);
        }
    };

    const int nk = Kpart / 32;
    stage(0, 0);
    __syncthreads();
    for (int kk = 0; kk < nk; ++kk) {
        if (kk + 1 < nk) stage((kk + 1) * 32, (kk + 1) & 1);   // in flight during MFMA
        const int buf = kk & 1;
        bf16x8 af[4], bfr[4];
        #pragma unroll
        for (int i = 0; i < 4; ++i)
            af[i] = *(const bf16x8*)(As[buf] + (wm * 64 + i * 16 + lr) * 32 + q * 8);
        #pragma unroll
        for (int j = 0; j < 4; ++j)
            bfr[j] = *(const bf16x8*)(Bs[buf] + (wn * 64 + j * 16 + lr) * 32 + q * 8);
        #pragma unroll
        for (int i = 0; i < 4; ++i)
            #pragma unroll
            for (int j = 0; j < 4; ++j)
                acc[i][j] = __builtin_amdgcn_mfma_f32_16x16x32_bf16(af[i], bfr[j], acc[i][j], 0, 0, 0);
        __syncthreads();   // drains prefetch (vmcnt) + protects buf reuse
    }
    float* Cz = C + (size_t)blockIdx.z * M * N;
    #pragma unroll
    for (int i = 0; i < 4; ++i) {
        const int mrow = m0 + wm * 64 + i * 16 + q * 4;
        #pragma unroll
        for (int j = 0; j < 4; ++j) {
            const int ncol = n0 + wn * 64 + j * 16 + lr;
            #pragma unroll
            for (int r = 0; r < 4; ++r)
                Cz[(size_t)(mrow + r) * N + ncol] = acc[i][j][r];
        }
    }
}

// ---------------------------------------------------------------------------
// dt_proj as MFMA GEMM with fused bias + softplus epilogue. (K=64, 2 iters)
// ---------------------------------------------------------------------------
__global__ __launch_bounds__(256) void gemm_dtsp(const __hip_bfloat16* __restrict__ A,
                                                 const __hip_bfloat16* __restrict__ B,
                                                 const float* __restrict__ bd,
                                                 float* __restrict__ delta) {
    __shared__ __hip_bfloat16 As[128 * 32];
    __shared__ __hip_bfloat16 Bs[128 * 32];
    const int t  = threadIdx.x;
    const int w  = t >> 6;
    const int ln = t & 63;
    const int wm = w >> 1, wn = w & 1;
    const int q  = ln >> 4, lr = ln & 15;
    const int m0 = blockIdx.y * 128;
    const int n0 = blockIdx.x * 128;
    const int lda = 128, ldb = 64, N = 2048;

    f32x4 acc[4][4] = {};
    const __hip_bfloat16* Ag = A + (size_t)m0 * lda;
    const __hip_bfloat16* Bg = B + (size_t)n0 * ldb;

    for (int k0 = 0; k0 < 64; k0 += 32) {
        #pragma unroll
        for (int i = 0; i < 2; ++i) {
            const int c = (i * 4 + w) * 64 + ln;
            const int r = c >> 2, col = (c & 3) * 8;
            __builtin_amdgcn_global_load_lds(
                (const __attribute__((address_space(1))) void*)(Ag + (size_t)r * lda + k0 + col),
                (__attribute__((address_space(3))) void*)(As + (i * 4 + w) * 64 * 8),
                16, 0, 0);
            __builtin_amdgcn_global_load_lds(
                (const __attribute__((address_space(1))) void*)(Bg + (size_t)r * ldb + k0 + col),
                (__attribute__((address_space(3))) void*)(Bs + (i * 4 + w) * 64 * 8),
                16, 0, 0);
        }
        __syncthreads();
        bf16x8 af[4], bfr[4];
        #pragma unroll
        for (int i = 0; i < 4; ++i)
            af[i] = *(const bf16x8*)(As + (wm * 64 + i * 16 + lr) * 32 + q * 8);
        #pragma unroll
        for (int j = 0; j < 4; ++j)
            bfr[j] = *(const bf16x8*)(Bs + (wn * 64 + j * 16 + lr) * 32 + q * 8);
        #pragma unroll
        for (int i = 0; i < 4; ++i)
            #pragma unroll
            for (int j = 0; j < 4; ++j)
                acc[i][j] = __builtin_amdgcn_mfma_f32_16x16x32_bf16(af[i], bfr[j], acc[i][j], 0, 0, 0);
        __syncthreads();
    }
    #pragma unroll
    for (int i = 0; i < 4; ++i) {
        const int mrow = m0 + wm * 64 + i * 16 + q * 4;
        #pragma unroll
        for (int j = 0; j < 4; ++j) {
            const int ncol = n0 + wn * 64 + j * 16 + lr;
            const float bias = bd[ncol];
            #pragma unroll
            for (int r = 0; r < 4; ++r) {
                float v = acc[i][j][r] + bias;
                float sp = (v > 20.f) ? v : log1pf(__expf(v));
                delta[(size_t)(mrow + r) * N + ncol] = sp;
            }
        }
    }
}

// ---------------------------------------------------------------------------
// Reduce 8 split-K partials of x_proj -> xdbl fp32 (1024x128) + xdblb bf16.
// ---------------------------------------------------------------------------
__global__ void xdbl_reduce_kernel(const float* __restrict__ part,
                                   float* __restrict__ xdbl,
                                   __hip_bfloat16* __restrict__ xdblb) {
    const int i = blockIdx.x * 256 + threadIdx.x;   // 1024*128
    float s = 0.f;
    #pragma unroll
    for (int z = 0; z < 8; ++z) s += part[(size_t)z * (1024 * 128) + i];
    xdbl[i] = s;
    xdblb[i] = __float2bfloat16(s);
}

// ---------------------------------------------------------------------------
// Fused fp32 -> bf16 casts for all weight/activation inputs.
// ---------------------------------------------------------------------------
#define R0 (1024 * 1024)
#define R1 (R0 + 4096 * 1024)
#define R2 (R1 + 2048 * 1024)
#define R3 (R2 + 128 * 2048)
#define R4 (R3 + 2048 * 64)
__global__ void cast_all_kernel(const float* __restrict__ x1,
                                const float* __restrict__ w_in,
                                const float* __restrict__ w_out,
                                const float* __restrict__ w_xp,
                                const float* __restrict__ w_dt,
                                __hip_bfloat16* __restrict__ xa,
                                __hip_bfloat16* __restrict__ wb1,
                                __hip_bfloat16* __restrict__ wob,
                                __hip_bfloat16* __restrict__ wpb,
                                __hip_bfloat16* __restrict__ wdb) {
    int i = blockIdx.x * 256 + threadIdx.x;
    if (i < R0) {
        xa[i] = __float2bfloat16(x1[i]);
    } else if (i < R1) {
        int j = i - R0; wb1[j] = __float2bfloat16(w_in[j]);
    } else if (i < R2) {
        int j = i - R1; wob[j] = __float2bfloat16(w_out[j]);
    } else if (i < R3) {
        int j = i - R2; int e = j >> 11;
        wpb[j] = __float2bfloat16(e < 96 ? w_xp[j] : 0.f);
    } else if (i < R4) {
        int j = i - R3; wdb[j] = __float2bfloat16(w_dt[j]);
    }
}

// ---------------------------------------------------------------------------
// Depthwise causal conv1d (k=4, left pad 3) + bias + SiLU.
// ---------------------------------------------------------------------------
__global__ void conv_silu_kernel(const float* __restrict__ xz,
                                 const float* __restrict__ conv_w,
                                 const float* __restrict__ conv_b,
                                 float* __restrict__ xs,
                                 __hip_bfloat16* __restrict__ xsb) {
    int idx = blockIdx.x * blockDim.x + threadIdx.x;  // (b*L + l)*DINNER + d
    int d = idx & (DINNER - 1);
    int l = (idx >> 11) & (SEQL - 1);
    int b = idx >> 19;
    const float w0 = conv_w[d * 4 + 0];
    const float w1 = conv_w[d * 4 + 1];
    const float w2 = conv_w[d * 4 + 2];
    const float w3 = conv_w[d * 4 + 3];
    float acc = conv_b[d];
    const size_t base = (size_t)(b * SEQL) * (2 * DINNER) + d;
    if (l >= 3) acc += w0 * xz[base + (size_t)(l - 3) * (2 * DINNER)];
    if (l >= 2) acc += w1 * xz[base + (size_t)(l - 2) * (2 * DINNER)];
    if (l >= 1) acc += w2 * xz[base + (size_t)(l - 1) * (2 * DINNER)];
    acc += w3 * xz[base + (size_t)l * (2 * DINNER)];
    float v = acc / (1.f + __expf(-acc));
    xs[idx] = v;
    xsb[idx] = __float2bfloat16(v);
}

// ---------------------------------------------------------------------------
// 16-lane row sum via DPP row_ror rotations (no DS ops).
// ---------------------------------------------------------------------------
__device__ __forceinline__ float row_reduce16(float x) {
    x += __int_as_float(__builtin_amdgcn_update_dpp(0, __float_as_int(x), 0x128, 0xF, 0xF, true));
    x += __int_as_float(__builtin_amdgcn_update_dpp(0, __float_as_int(x), 0x124, 0xF, 0xF, true));
    x += __int_as_float(__builtin_amdgcn_update_dpp(0, __float_as_int(x), 0x122, 0xF, 0xF, true));
    x += __int_as_float(__builtin_amdgcn_update_dpp(0, __float_as_int(x), 0x121, 0xF, 0xF, true));
    return x;
}

// ---------------------------------------------------------------------------
// Chunk-parallel selective scan, phase A: per-chunk local recurrence.
// h_l = e_l h_{l-1} + u_l b_l starting from h=0 over 64 steps; emits
// L = local result, P = prod(e). Grid (128, B, NCHUNK) = 2048 blocks
// -> 32 waves/CU (4x the old occupancy). Whole window staged in LDS once.
// ---------------------------------------------------------------------------
__global__ __launch_bounds__(256) void scan_carry_kernel(const float* __restrict__ delta,
                                                         const float* __restrict__ xs,
                                                         const float* __restrict__ xdbl,
                                                         const float* __restrict__ A_log,
                                                         float* __restrict__ carryL,
                                                         float* __restrict__ carryP) {
    __shared__ float sDU[CH][16][2];   // [l][dl][{dv, dv*xv}]
    __shared__ float sB[CH][16];       // [l][n]
    const int b = blockIdx.y, c = blockIdx.z, dg = blockIdx.x;
    const int t = threadIdx.x;
    const int dl = t >> 4, n = t & 15;
    const int d = dg * 16 + dl;
    const float a = -__expf(A_log[d * DSTATE + n]);
    const int srow = t >> 4, scol = t & 15;
    const int sd = dg * 16 + scol;
    const int rowbase = b * SEQL + c * CH;
    #pragma unroll
    for (int i = 0; i < 4; ++i) {
        const int row = rowbase + i * 16 + srow;
        const float dv = delta[(size_t)row * DINNER + sd];
        const float xv = xs[(size_t)row * DINNER + sd];
        sDU[i * 16 + srow][scol][0] = dv;
        sDU[i * 16 + srow][scol][1] = dv * xv;
        sB[i * 16 + srow][scol] = xdbl[row * 128 + 64 + scol];
    }
    __syncthreads();
    float h = 0.f, P = 1.f;
    #pragma unroll 16
    for (int l = 0; l < CH; ++l) {
        const float e = __expf(sDU[l][dl][0] * a);
        h = e * h + sDU[l][dl][1] * sB[l][n];
        P *= e;
    }
    const size_t ci = (((size_t)(b * NCHUNK + c)) * DINNER + d) * DSTATE + n;
    carryL[ci] = h;
    carryP[ci] = P;
}

// ---------------------------------------------------------------------------
// Chunk-parallel selective scan, phase B: combine carries (h = P_j h + L_j,
// j < c) then run the 64-step scan with y output (+D*xs, *silu(res), bf16).
// ---------------------------------------------------------------------------
__global__ __launch_bounds__(256) void scan_apply_kernel(const float* __restrict__ delta,
                                                         const float* __restrict__ xs,
                                                         const float* __restrict__ xdbl,
                                                         const float* __restrict__ xz,
                                                         const float* __restrict__ A_log,
                                                         const float* __restrict__ Dp,
                                                         const float* __restrict__ carryL,
                                                         const float* __restrict__ carryP,
                                                         __hip_bfloat16* __restrict__ ybb) {
    __shared__ float sDU[CH][16][2];   // [l][dl][{dv, dv*xv}]
    __shared__ float sBC[CH][16][2];   // [l][n][{B, C}]
    __shared__ float sGW[CH][16][2];   // [l][dl][{g, D*xv*g}]
    const int b = blockIdx.y, c = blockIdx.z, dg = blockIdx.x;
    const int t = threadIdx.x;
    const int dl = t >> 4, n = t & 15;
    const int d = dg * 16 + dl;
    const float a = -__expf(A_log[d * DSTATE + n]);
    const int srow = t >> 4, scol = t & 15;
    const int sd = dg * 16 + scol;
    const float Dstage = Dp[sd];
    const int rowbase = b * SEQL + c * CH;
    #pragma unroll
    for (int i = 0; i < 4; ++i) {
        const int row = rowbase + i * 16 + srow;
        const float dv = delta[(size_t)row * DINNER + sd];
        const float xv = xs[(size_t)row * DINNER + sd];
        const float r  = xz[(size_t)row * (2 * DINNER) + DINNER + sd];
        const float g = r / (1.f + __expf(-r));
        const int lr_ = i * 16 + srow;
        sDU[lr_][scol][0] = dv;
        sDU[lr_][scol][1] = dv * xv;
        sGW[lr_][scol][0] = g;
        sGW[lr_][scol][1] = Dstage * xv * g;
        sBC[lr_][scol][0] = xdbl[row * 128 + 64 + scol];
        sBC[lr_][scol][1] = xdbl[row * 128 + 80 + scol];
    }
    __syncthreads();
    // carry combine: h_start(c) via h = P_j*h + L_j for j = 0..c-1 (uniform branch)
    float h = 0.f;
    for (int j = 0; j < c; ++j) {
        const size_t ci = (((size_t)(b * NCHUNK + j)) * DINNER + d) * DSTATE + n;
        h = carryP[ci] * h + carryL[ci];
    }
    #pragma unroll 16
    for (int l = 0; l < CH; ++l) {
        const float e = __expf(sDU[l][dl][0] * a);
        h = e * h + sDU[l][dl][1] * sBC[l][n][0];
        float p = row_reduce16(h * sBC[l][n][1]);
        if (n == 0) {
            const float y = p * sGW[l][dl][0] + sGW[l][dl][1];
            ybb[(size_t)(rowbase + l) * DINNER + d] = __float2bfloat16(y);
        }
    }
}

// ---------------------------------------------------------------------------
// LayerNorm over last dim (1024), fused 4-way split-K reduce of out_proj
// partials. block per row, 256 threads x 4 elems.
// ---------------------------------------------------------------------------
__global__ __launch_bounds__(256) void ln_kernel(const float* __restrict__ opart,
                                                 const float* __restrict__ lw,
                                                 const float* __restrict__ lb,
                                                 float* __restrict__ out) {
    __shared__ float red[8];
    const int row = blockIdx.x;
    const int t = threadIdx.x;
    float v[4];
    float s = 0.f, s2 = 0.f;
    #pragma unroll
    for (int i = 0; i < 4; ++i) {
        const int c = t + 256 * i;
        float acc = 0.f;
        #pragma unroll
        for (int z = 0; z < 4; ++z)
            acc += opart[(size_t)z * (1024 * 1024) + (size_t)row * OUTC + c];
        v[i] = acc;
        s += acc;
        s2 += acc * acc;
    }
    #pragma unroll
    for (int o = 32; o; o >>= 1) {
        s += __shfl_down(s, o);
        s2 += __shfl_down(s2, o);
    }
    const int wid = t >> 6;
    if ((t & 63) == 0) { red[wid] = s; red[4 + wid] = s2; }
    __syncthreads();
    if (t == 0) {
        float ts = red[0] + red[1] + red[2] + red[3];
        float ts2 = red[4] + red[5] + red[6] + red[7];
        float mu = ts * (1.f / OUTC);
        float var = ts2 * (1.f / OUTC) - mu * mu;
        red[0] = mu;
        red[1] = rsqrtf(var + 1e-5f);
    }
    __syncthreads();
    const float mu = red[0], rs = red[1];
    #pragma unroll
    for (int i = 0; i < 4; ++i) {
        const int c = t + 256 * i;
        out[(size_t)row * OUTC + c] = (v[i] - mu) * rs * lw[c] + lb[c];
    }
}

// ---------------------------------------------------------------------------
extern "C" void kernel_launch(void* const* d_in, const int* in_sizes, int n_in,
                              void* d_out, int out_size, void* d_ws, size_t ws_size,
                              hipStream_t stream) {
    const float* x1        = (const float*)d_in[0];   // (1024,1024)
    const float* in_proj_w = (const float*)d_in[1];   // (4096,1024)
    const float* conv_w    = (const float*)d_in[2];   // (2048,1,4)
    const float* conv_b    = (const float*)d_in[3];   // (2048,)
    const float* x_proj_w  = (const float*)d_in[4];   // (96,2048)
    const float* dt_proj_w = (const float*)d_in[5];   // (2048,64)
    const float* dt_proj_b = (const float*)d_in[6];   // (2048,)
    const float* A_log     = (const float*)d_in[7];   // (2048,16)
    const float* Dp        = (const float*)d_in[8];   // (2048,)
    const float* out_proj_w= (const float*)d_in[9];   // (1024,2048)
    const float* ln_w      = (const float*)d_in[10];  // (1024,)
    const float* ln_b      = (const float*)d_in[11];  // (1024,)
    float* out = (float*)d_out;

    // workspace carve-up
    char* p = (char*)d_ws;
    __hip_bfloat16* xa    = (__hip_bfloat16*)p; p += (size_t)1024 * 1024 * 2;  // 2 MB
    __hip_bfloat16* wb1   = (__hip_bfloat16*)p; p += (size_t)4096 * 1024 * 2;  // 8 MB
    __hip_bfloat16* wpb   = (__hip_bfloat16*)p; p += (size_t)128 * 2048 * 2;   // 0.5 MB
    __hip_bfloat16* wob   = (__hip_bfloat16*)p; p += (size_t)1024 * 2048 * 2;  // 4 MB
    __hip_bfloat16* wdb   = (__hip_bfloat16*)p; p += (size_t)2048 * 64 * 2;    // 0.25 MB
    __hip_bfloat16* xsb   = (__hip_bfloat16*)p; p += (size_t)1024 * 2048 * 2;  // 4 MB
    __hip_bfloat16* ybb   = (__hip_bfloat16*)p; p += (size_t)1024 * 2048 * 2;  // 4 MB
    __hip_bfloat16* xdblb = (__hip_bfloat16*)p; p += (size_t)1024 * 128 * 2;   // 0.25 MB
    float* xz    = (float*)p; p += (size_t)1024 * 4096 * 4;                    // 16 MB
    float* xs    = (float*)p; p += (size_t)1024 * 2048 * 4;                    // 8 MB
    float* xdbl  = (float*)p; p += (size_t)1024 * 128 * 4;                     // 0.5 MB
    float* xpart = (float*)p; p += (size_t)8 * 1024 * 128 * 4;                 // 4 MB
    float* delta = (float*)p; p += (size_t)1024 * 2048 * 4;                    // 8 MB
    float* carryL = (float*)p; p += (size_t)BATCH * NCHUNK * DINNER * DSTATE * 4; // 2 MB
    float* carryP = (float*)p; p += (size_t)BATCH * NCHUNK * DINNER * DSTATE * 4; // 2 MB
    // out_proj partials (16 MB) alias xz: scan (last reader of xz) precedes
    // out_proj in stream order.
    float* opart = xz;

    // 0. fused bf16 casts
    cast_all_kernel<<<(R4 + 255) / 256, 256, 0, stream>>>(x1, in_proj_w, out_proj_w,
                                                          x_proj_w, dt_proj_w,
                                                          xa, wb1, wob, wpb, wdb);
    // 1. in_proj: xz = xa @ wb1^T   (1024 x 4096, K=1024)
    gemm_mfma<<<dim3(32, 8, 1), 256, 0, stream>>>(xa, wb1, xz,
                                                  NROWS, 2 * DINNER, DMODEL, DMODEL, DMODEL);
    // 2. depthwise causal conv + SiLU -> xs (fp32) + xsb (bf16)
    conv_silu_kernel<<<(NROWS * DINNER) / 256, 256, 0, stream>>>(xz, conv_w, conv_b, xs, xsb);
    // 3. x_proj: xpart[z] = xsb @ wpb^T partials (1024 x 128, K=2048, split 8)
    gemm_mfma<<<dim3(1, 8, 8), 256, 0, stream>>>(xsb, wpb, xpart,
                                                 NROWS, 128, DINNER, DINNER, DINNER);
    xdbl_reduce_kernel<<<(1024 * 128) / 256, 256, 0, stream>>>(xpart, xdbl, xdblb);
    // 4. dt_proj + softplus -> delta (MFMA, K=64)
    gemm_dtsp<<<dim3(16, 8), 256, 0, stream>>>(xdblb, wdb, dt_proj_b, delta);
    // 5a. scan phase A: per-chunk carries (2048 blocks, 32 waves/CU)
    scan_carry_kernel<<<dim3(DINNER / 16, BATCH, NCHUNK), 256, 0, stream>>>(
        delta, xs, xdbl, A_log, carryL, carryP);
    // 5b. scan phase B: combine + apply + gate -> ybb (bf16)
    scan_apply_kernel<<<dim3(DINNER / 16, BATCH, NCHUNK), 256, 0, stream>>>(
        delta, xs, xdbl, xz, A_log, Dp, carryL, carryP, ybb);
    // 6. out_proj partials: opart[z] = ybb @ wob^T (1024 x 1024, K=2048, split 4)
    gemm_mfma<<<dim3(8, 8, 4), 256, 0, stream>>>(ybb, wob, opart,
                                                 NROWS, OUTC, DINNER, DINNER, DINNER);
    // 7. LayerNorm (+ split-K reduce) -> out
    ln_kernel<<<NROWS, 256, 0, stream>>>(opart, ln_w, ln_b, out);
}